// Round 1
// baseline (1497.873 us; speedup 1.0000x reference)
//
#include <hip/hip_runtime.h>
#include <stdint.h>

#define B_    1024
#define LSEQ  128
#define LM1   127
#define CIN   8
#define HID   64
#define MLPH  128
#define INITH 20
#define RPB   4      // batch rows per block
#define NTHR  256

typedef _Float16 half2_t __attribute__((ext_vector_type(2)));

__device__ __forceinline__ float fdot2(uint32_t a, uint32_t b, float c) {
#if __has_builtin(__builtin_amdgcn_fdot2)
  return __builtin_amdgcn_fdot2(__builtin_bit_cast(half2_t, a),
                                __builtin_bit_cast(half2_t, b), c, false);
#else
  half2_t av = __builtin_bit_cast(half2_t, a);
  half2_t bv = __builtin_bit_cast(half2_t, b);
  return c + (float)av.x * (float)bv.x + (float)av.y * (float)bv.y;
#endif
}

__device__ __forceinline__ float fast_tanh(float x) {
  // tanh(x) = 1 - 2/(exp(2x)+1); saturates correctly at +/-inf via v_exp/v_rcp
  float e = __expf(2.0f * x);
  return 1.0f - 2.0f * __builtin_amdgcn_rcpf(e + 1.0f);
}

// One persistent block per RPB batch rows; full 127-step RK4 scan inside.
// LDS: W2 packed half2 [kpair][colgroup4][hx] (131 KB), W1 packed half2 over
// z-pairs (16 KB), h/zs as fp16 scratch re-read as packed uint broadcasts.
__global__ void __launch_bounds__(NTHR, 1) cde_kernel(
    const float* __restrict__ coeffs,
    const float* __restrict__ Wi1, const float* __restrict__ bi1,
    const float* __restrict__ Wi2, const float* __restrict__ bi2,
    const float* __restrict__ W1,  const float* __restrict__ b1,
    const float* __restrict__ W2,  const float* __restrict__ b2,
    float* __restrict__ out)
{
  __shared__ uint4    W2x4[64 * 2 * 64];   // 131072 B: [kp][cg][hx], 4 half2 cols each
  __shared__ uint32_t W1p[32 * MLPH];      // 16384 B: pairs over z-k for each j
  __shared__ float    w1t[MLPH];           // W1 row 0 (t coefficient)
  __shared__ float    b1s[MLPH];
  __shared__ _Float16 zsph[RPB * HID];     // stage input z, fp16
  __shared__ _Float16 hph[RPB * MLPH];     // hidden h, fp16
  __shared__ float    gb[3][RPB][CIN];     // dXdt at t, t+0.5, t+1

  const int t   = threadIdx.x;
  const int r   = t >> 6;        // 0..3  (phase A/C row)
  const int hx  = t & 63;        // 0..63 (hidden index)
  const int row = blockIdx.x * RPB + r;

  // ---- one-time: stage packed weights into LDS ----
  {
    uint32_t* W2u = (uint32_t*)W2x4;
    for (int u = t; u < 64 * 2 * 64 * 4; u += NTHR) {
      int kp = u >> 9;
      int cg = (u >> 8) & 1;
      int hxx = (u >> 2) & 63;
      int cw = u & 3;
      int col = hxx * 8 + cg * 4 + cw;
      float v0 = W2[(2 * kp) * 512 + col];
      float v1 = W2[(2 * kp + 1) * 512 + col];
      half2_t hh = { (_Float16)v0, (_Float16)v1 };
      W2u[u] = __builtin_bit_cast(uint32_t, hh);
    }
    for (int u = t; u < 32 * MLPH; u += NTHR) {
      int m = u >> 7, j = u & 127;
      float v0 = W1[(1 + 2 * m) * MLPH + j];
      float v1 = W1[(2 + 2 * m) * MLPH + j];
      half2_t hh = { (_Float16)v0, (_Float16)v1 };
      W1p[u] = __builtin_bit_cast(uint32_t, hh);
    }
    if (t < MLPH) { w1t[t] = W1[t]; b1s[t] = b1[t]; }
  }

  // b2 for this thread's 8 output channels, kept in registers
  float b2r[CIN];
  #pragma unroll
  for (int c = 0; c < CIN; ++c) b2r[c] = b2[hx * CIN + c];

  // ---- init z0 = tanh(relu(X0@Wi1+bi1)@Wi2+bi2) ----
  float z;
  {
    float x0[CIN];
    const float* cb = coeffs + (size_t)row * (LM1 * 32);
    #pragma unroll
    for (int c = 0; c < CIN; ++c) x0[c] = cb[c];   // 'a' channels 0..7, l=0
    float acc = bi2[hx];
    for (int j = 0; j < INITH; ++j) {
      float u = bi1[j];
      #pragma unroll
      for (int c = 0; c < CIN; ++c) u += x0[c] * Wi1[c * INITH + j];
      u = fmaxf(u, 0.0f);
      acc += u * Wi2[j * HID + hx];
    }
    z = fast_tanh(acc);
  }
  out[(size_t)row * (LSEQ * HID) + hx] = z;

  for (int i = 0; i < LM1; ++i) {
    __syncthreads();  // protect gb vs previous step's readers
    // dXdt(t) at fr=0 (g1), fr=0.5 (g2), and t+1 (g4)
    if (t < RPB * CIN) {
      int rg = t >> 3, cg = t & 7;
      const float* cb = coeffs + (size_t)(blockIdx.x * RPB + rg) * (LM1 * 32) + (size_t)i * 32;
      float bb = cb[8 + cg], cc = cb[16 + cg], dd = cb[24 + cg];
      gb[0][rg][cg] = bb;
      gb[1][rg][cg] = bb + cc + 0.75f * dd;
      gb[2][rg][cg] = (i < LM1 - 1) ? cb[32 + 8 + cg]
                                    : (bb + 2.0f * cc + 3.0f * dd);
    }

    float ksum = 0.0f, kprev = 0.0f;
    #pragma unroll
    for (int s = 0; s < 4; ++s) {
      const float coef = (s == 0) ? 0.0f : (s == 3) ? 1.0f : 0.5f;
      const float ts   = (float)i + ((s == 0) ? 0.0f : (s == 3) ? 1.0f : 0.5f);
      const int   gi   = (s == 0) ? 0 : (s == 3) ? 2 : 1;

      // Phase A: stage input zs -> fp16 LDS
      float zs = z + coef * kprev;
      zsph[t] = (_Float16)zs;
      __syncthreads();

      // Phase B: h[rb][j] = relu(ts*W1[0][j] + sum_k zs[k]*W1[1+k][j] + b1[j])
      {
        const int j  = t & 127;
        const int rr = t >> 7;
        #pragma unroll
        for (int rb2 = 0; rb2 < 2; ++rb2) {
          int rb = rr + rb2 * 2;
          float acc = ts * w1t[j] + b1s[j];
          const uint32_t* zp = (const uint32_t*)(zsph + rb * HID);
          #pragma unroll
          for (int m = 0; m < 32; ++m)
            acc = fdot2(W1p[m * MLPH + j], zp[m], acc);
          acc = fmaxf(acc, 0.0f);
          hph[rb * MLPH + j] = (_Float16)acc;
        }
      }
      __syncthreads();

      // Phase C: f cols hx*8..hx*8+7 = tanh(h@W2+b2); vf = sum_c f*g
      float accs[CIN];
      #pragma unroll
      for (int c = 0; c < CIN; ++c) accs[c] = b2r[c];
      {
        const uint32_t* hp = (const uint32_t*)(hph + r * MLPH);
        const uint4* wrow = W2x4 + hx;
        #pragma unroll 16
        for (int kp = 0; kp < 64; ++kp) {
          uint32_t hpair = hp[kp];                 // broadcast (same for wave)
          uint4 wa = wrow[(kp * 2 + 0) * 64];      // 16B/lane, 16B lane stride
          uint4 wb = wrow[(kp * 2 + 1) * 64];
          accs[0] = fdot2(wa.x, hpair, accs[0]);
          accs[1] = fdot2(wa.y, hpair, accs[1]);
          accs[2] = fdot2(wa.z, hpair, accs[2]);
          accs[3] = fdot2(wa.w, hpair, accs[3]);
          accs[4] = fdot2(wb.x, hpair, accs[4]);
          accs[5] = fdot2(wb.y, hpair, accs[5]);
          accs[6] = fdot2(wb.z, hpair, accs[6]);
          accs[7] = fdot2(wb.w, hpair, accs[7]);
        }
      }
      float kc = 0.0f;
      #pragma unroll
      for (int c = 0; c < CIN; ++c)
        kc += fast_tanh(accs[c]) * gb[gi][r][c];
      kprev = kc;
      ksum += ((s == 1 || s == 2) ? 2.0f : 1.0f) * kc;
    }
    z += ksum * (1.0f / 6.0f);
    out[(size_t)row * (LSEQ * HID) + (size_t)(i + 1) * HID + hx] = z;
  }
}

extern "C" void kernel_launch(void* const* d_in, const int* in_sizes, int n_in,
                              void* d_out, int out_size, void* d_ws, size_t ws_size,
                              hipStream_t stream) {
  const float* coeffs = (const float*)d_in[0];
  const float* Wi1    = (const float*)d_in[1];
  const float* bi1    = (const float*)d_in[2];
  const float* Wi2    = (const float*)d_in[3];
  const float* bi2    = (const float*)d_in[4];
  const float* W1     = (const float*)d_in[5];
  const float* b1     = (const float*)d_in[6];
  const float* W2     = (const float*)d_in[7];
  const float* b2     = (const float*)d_in[8];
  float* out          = (float*)d_out;
  (void)in_sizes; (void)n_in; (void)out_size; (void)d_ws; (void)ws_size;
  cde_kernel<<<B_ / RPB, NTHR, 0, stream>>>(coeffs, Wi1, bi1, Wi2, bi2,
                                            W1, b1, W2, b2, out);
}

// Round 2
// 659.167 us; speedup vs baseline: 2.2724x; 2.2724x over previous
//
#include <hip/hip_runtime.h>
#include <stdint.h>

#define LM1   127
#define NTHR  256

typedef _Float16 half2_t __attribute__((ext_vector_type(2)));
typedef _Float16 half8_t __attribute__((ext_vector_type(8)));
typedef float    f32x4  __attribute__((ext_vector_type(4)));

__device__ __forceinline__ float fdot2(uint32_t a, uint32_t b, float c) {
  return __builtin_amdgcn_fdot2(__builtin_bit_cast(half2_t, a),
                                __builtin_bit_cast(half2_t, b), c, false);
}
__device__ __forceinline__ uint32_t packh2(float a, float b) {
  half2_t h = {(_Float16)a, (_Float16)b};
  return __builtin_bit_cast(uint32_t, h);
}
__device__ __forceinline__ float fast_tanh(float x) {
  float e = __expf(2.0f * x);
  return 1.0f - 2.0f * __builtin_amdgcn_rcpf(e + 1.0f);
}

// Persistent block per 4 batch rows. Phase C = MFMA 16x16x32 f16 with W2
// held in registers as B-fragments (zero per-stage LDS traffic for W2).
// z ownership: thread t -> (hx = wave*16 + (lane>>2), r = lane&3) so each
// wave consumes its own D tiles (within-wave LDS handoff, no barrier).
__global__ void __launch_bounds__(NTHR, 1) cde_kernel(
    const float* __restrict__ coeffs,
    const float* __restrict__ Wi1, const float* __restrict__ bi1,
    const float* __restrict__ Wi2, const float* __restrict__ bi2,
    const float* __restrict__ W1,  const float* __restrict__ b1,
    const float* __restrict__ W2,  const float* __restrict__ b2,
    float* __restrict__ out)
{
  __shared__ _Float16 hA[16 * 136];   // A-operand layout [m][k], row stride 136 (2-way-free banks)
  __shared__ _Float16 zsb[4 * 64];    // stage-input z, fp16, [r][hx]
  __shared__ float    fbuf[4 * 576];  // per-wave D scratch: word = 4*col + 4*(col>>3) + m
  __shared__ float    gds[3][4][8];   // dXdt at fr=0, 0.5, 1.0

  const int t    = threadIdx.x;
  const int lane = t & 63;
  const int w    = t >> 6;        // wave id = phase-B row = col-block owner
  const int r    = lane & 3;      // batch row owned
  const int hxl  = lane >> 2;     // 0..15
  const int hx   = w * 16 + hxl;  // hidden index owned
  const int row0 = blockIdx.x * 4;

  // ---- zero A rows 4..15 (stay zero forever; rows 0..3 rewritten per stage)
  {
    uint32_t* h32 = (uint32_t*)hA;
    for (int u = t; u < 16 * 136 / 2; u += NTHR) h32[u] = 0u;
  }

  // ---- W1 -> registers: this thread's 2 fixed h-columns j2, j2+1
  const int j2 = 2 * lane;
  uint32_t w1A[32], w1B[32];
  #pragma unroll 8
  for (int m = 0; m < 32; ++m) {
    w1A[m] = packh2(W1[(1 + 2 * m) * 128 + j2],     W1[(2 + 2 * m) * 128 + j2]);
    w1B[m] = packh2(W1[(1 + 2 * m) * 128 + j2 + 1], W1[(2 + 2 * m) * 128 + j2 + 1]);
  }
  const float w1t0 = W1[j2], w1t1 = W1[j2 + 1];
  const float b10  = b1[j2], b11  = b1[j2 + 1];

  // ---- b2 for owned columns
  float b2r[8];
  #pragma unroll
  for (int c = 0; c < 8; ++c) b2r[c] = b2[hx * 8 + c];

  // ---- W2 -> registers as B-fragments: B[n = lane&15][k = (lane>>4)*8 + j]
  half8_t bf[8][4];
  {
    const int ncol = w * 128 + (lane & 15);
    const int kq   = (lane >> 4) * 8;
    #pragma unroll
    for (int nt = 0; nt < 8; ++nt)
      #pragma unroll
      for (int kt = 0; kt < 4; ++kt)
        #pragma unroll
        for (int j = 0; j < 8; ++j)
          bf[nt][kt][j] = (_Float16)W2[(kt * 32 + kq + j) * 512 + ncol + nt * 16];
  }

  // ---- z0 = tanh(relu(X0@Wi1+bi1)@Wi2+bi2)
  float z;
  {
    const float* cb = coeffs + (size_t)(row0 + r) * (LM1 * 32);
    float x0[8];
    #pragma unroll
    for (int c = 0; c < 8; ++c) x0[c] = cb[c];
    float acc = bi2[hx];
    for (int j = 0; j < 20; ++j) {
      float u = bi1[j];
      #pragma unroll
      for (int c = 0; c < 8; ++c) u += x0[c] * Wi1[c * 20 + j];
      u = fmaxf(u, 0.0f);
      acc += u * Wi2[j * 64 + hx];
    }
    z = fast_tanh(acc);
  }
  out[(size_t)(row0 + r) * 8192 + hx] = z;

  float* const fw = fbuf + w * 576;

  for (int i = 0; i < LM1; ++i) {
    __syncthreads();  // prev step's kc readers done before gds rewrite
    if (t < 32) {
      const int rg = t >> 3, cg = t & 7;
      const float* cb = coeffs + (size_t)(row0 + rg) * (LM1 * 32) + (size_t)i * 32;
      const float bb = cb[8 + cg], cc = cb[16 + cg], dd = cb[24 + cg];
      gds[0][rg][cg] = bb;
      gds[1][rg][cg] = bb + cc + 0.75f * dd;
      gds[2][rg][cg] = (i < LM1 - 1) ? cb[32 + 8 + cg]
                                     : (bb + 2.0f * cc + 3.0f * dd);
    }

    float ksum = 0.0f, kprev = 0.0f;
    #pragma unroll
    for (int s = 0; s < 4; ++s) {
      const float coef = (s == 0) ? 0.0f : (s == 3) ? 1.0f : 0.5f;
      const float ts   = (float)i + ((s == 0) ? 0.0f : (s == 3) ? 1.0f : 0.5f);
      const int   gi   = (s == 0) ? 0 : (s == 3) ? 2 : 1;

      // Phase A: stage input -> fp16 LDS
      zsb[r * 64 + hx] = (_Float16)(z + coef * kprev);
      __syncthreads();

      // Phase B: h[w][j2], h[w][j2+1]  (W1 in regs, zs as 8 b128 broadcasts)
      {
        uint32_t zz[32];
        const uint4* zq = (const uint4*)(zsb + w * 64);
        #pragma unroll
        for (int q = 0; q < 8; ++q) {
          uint4 v = zq[q];
          zz[4 * q] = v.x; zz[4 * q + 1] = v.y; zz[4 * q + 2] = v.z; zz[4 * q + 3] = v.w;
        }
        float a0 = ts * w1t0 + b10, a1 = ts * w1t1 + b11;
        float a0b = 0.0f, a1b = 0.0f;
        #pragma unroll
        for (int m = 0; m < 32; m += 2) {
          a0  = fdot2(w1A[m],     zz[m],     a0);
          a1  = fdot2(w1B[m],     zz[m],     a1);
          a0b = fdot2(w1A[m + 1], zz[m + 1], a0b);
          a1b = fdot2(w1B[m + 1], zz[m + 1], a1b);
        }
        const float h0 = fmaxf(a0 + a0b, 0.0f);
        const float h1 = fmaxf(a1 + a1b, 0.0f);
        *(uint32_t*)(hA + w * 136 + 2 * lane) = packh2(h0, h1);
      }
      __syncthreads();

      // Phase C: D = h @ W2 via MFMA; A-frag: A[m=lane&15][k=(lane>>4)*8+j]
      {
        uint4 afu[4];
        const _Float16* hap = hA + (lane & 15) * 136 + (lane >> 4) * 8;
        #pragma unroll
        for (int kt = 0; kt < 4; ++kt)
          afu[kt] = *(const uint4*)(hap + kt * 32);

        f32x4 dacc[8];
        #pragma unroll
        for (int np = 0; np < 4; ++np) {   // 2 n-tiles at a time for MFMA ILP
          f32x4 d0 = {0.f, 0.f, 0.f, 0.f};
          f32x4 d1 = {0.f, 0.f, 0.f, 0.f};
          #pragma unroll
          for (int kt = 0; kt < 4; ++kt) {
            half8_t a = __builtin_bit_cast(half8_t, afu[kt]);
            d0 = __builtin_amdgcn_mfma_f32_16x16x32_f16(a, bf[2 * np][kt],     d0, 0, 0, 0);
            d1 = __builtin_amdgcn_mfma_f32_16x16x32_f16(a, bf[2 * np + 1][kt], d1, 0, 0, 0);
          }
          dacc[2 * np] = d0; dacc[2 * np + 1] = d1;
        }
        if (lane < 16) {    // rows m=0..3 live on lanes 0..15 (reg = m)
          #pragma unroll
          for (int nt = 0; nt < 8; ++nt) {
            const int cl = nt * 16 + lane;
            *(f32x4*)(fw + 4 * cl + 4 * (cl >> 3)) = dacc[nt];
          }
        }
      }
      // within-wave handoff: drain own LDS stores before reading
      asm volatile("s_waitcnt lgkmcnt(0)" ::: "memory");

      // kc: read own 8 channels, +b2, tanh, dot with g   (conflict-free: bank = 4*(hxl+c)+r)
      {
        const f32x4 ga = *(const f32x4*)&gds[gi][r][0];
        const f32x4 gb4 = *(const f32x4*)&gds[gi][r][4];
        const float gg[8] = {ga.x, ga.y, ga.z, ga.w, gb4.x, gb4.y, gb4.z, gb4.w};
        const float* fr_ = fw + 36 * hxl + r;
        float kcv = 0.0f;
        #pragma unroll
        for (int c = 0; c < 8; ++c)
          kcv += fast_tanh(fr_[4 * c] + b2r[c]) * gg[c];
        kprev = kcv;
        ksum += ((s == 1 || s == 2) ? 2.0f : 1.0f) * kcv;
      }
    }
    z += ksum * (1.0f / 6.0f);
    out[(size_t)(row0 + r) * 8192 + (size_t)(i + 1) * 64 + hx] = z;
  }
}

extern "C" void kernel_launch(void* const* d_in, const int* in_sizes, int n_in,
                              void* d_out, int out_size, void* d_ws, size_t ws_size,
                              hipStream_t stream) {
  const float* coeffs = (const float*)d_in[0];
  const float* Wi1    = (const float*)d_in[1];
  const float* bi1    = (const float*)d_in[2];
  const float* Wi2    = (const float*)d_in[3];
  const float* bi2    = (const float*)d_in[4];
  const float* W1     = (const float*)d_in[5];
  const float* b1     = (const float*)d_in[6];
  const float* W2     = (const float*)d_in[7];
  const float* b2     = (const float*)d_in[8];
  float* out          = (float*)d_out;
  (void)in_sizes; (void)n_in; (void)out_size; (void)d_ws; (void)ws_size;
  cde_kernel<<<256, NTHR, 0, stream>>>(coeffs, Wi1, bi1, Wi2, bi2,
                                       W1, b1, W2, b2, out);
}

// Round 3
// 594.979 us; speedup vs baseline: 2.5175x; 1.1079x over previous
//
#include <hip/hip_runtime.h>
#include <stdint.h>

#define LM1  127
#define NTHR 512

typedef _Float16 half8_t __attribute__((ext_vector_type(8)));
typedef float    f32x4   __attribute__((ext_vector_type(4)));

__device__ __forceinline__ float fast_tanh(float x) {
  float e = __expf(2.0f * x);
  return 1.0f - 2.0f * __builtin_amdgcn_rcpf(e + 1.0f);
}

// 256 blocks x 4 rows x 8 waves (2 waves/SIMD). Both MLP layers via MFMA
// 16x16x32 f16 with weights resident in registers as B-fragments.
// Phase B: wave w owns h-cols [16w,16w+16)  (2 MFMA).
// Phase C: wave w owns f-cols [64w,64w+64)  (16 MFMA, 4 acc chains).
// kc owners: lanes 0..31 of wave w -> (r=lane&3, hx=w*8+(lane>>2)); their 8
// channels hx*8+c all lie in wave w's D tiles -> within-wave LDS handoff.
__global__ void __launch_bounds__(NTHR, 2) cde_kernel(
    const float* __restrict__ coeffs,
    const float* __restrict__ Wi1, const float* __restrict__ bi1,
    const float* __restrict__ Wi2, const float* __restrict__ bi2,
    const float* __restrict__ W1,  const float* __restrict__ b1,
    const float* __restrict__ W2,  const float* __restrict__ b2,
    float* __restrict__ out)
{
  __shared__ _Float16 zsb[16 * 72];    // zs in A-layout [m][k], stride 72 halves
  __shared__ _Float16 hA [16 * 136];   // h  in A-layout [m][k], stride 136 halves
  __shared__ float    fwb[8][284];     // per-wave D scratch: word = 36*hxl + 4c + r
  __shared__ float    gds[2][3][4][8]; // double-buffered dXdt at fr=0,0.5,1

  const int t    = threadIdx.x;
  const int lane = t & 63;
  const int w    = t >> 6;             // wave 0..7
  const int l15  = lane & 15;
  const int lq   = lane >> 4;          // quad 0..3
  const int r    = lane & 3;
  const int hxl  = (lane >> 2) & 7;    // owner sub-index (lanes 0..31)
  const int hx   = w * 8 + hxl;
  const int row0 = blockIdx.x * 4;
  const bool owner = (lane < 32);

  // zero A-layout buffers once (rows 4..15 stay zero forever)
  for (int u = t; u < 16 * 72 / 2;  u += NTHR) ((uint32_t*)zsb)[u] = 0u;
  for (int u = t; u < 16 * 136 / 2; u += NTHR) ((uint32_t*)hA)[u]  = 0u;

  // ---- W1 -> B-fragments (K=64 -> 2 k-tiles), + epilogue constants
  half8_t bB[2];
  #pragma unroll
  for (int kt = 0; kt < 2; ++kt)
    #pragma unroll
    for (int j = 0; j < 8; ++j)
      bB[kt][j] = (_Float16)W1[(1 + kt * 32 + lq * 8 + j) * 128 + w * 16 + l15];
  const float w1t_c = W1[w * 16 + l15];
  const float b1_c  = b1[w * 16 + l15];

  // ---- W2 -> B-fragments: 4 n-tiles x 4 k-tiles
  half8_t bf[4][4];
  #pragma unroll
  for (int nt = 0; nt < 4; ++nt)
    #pragma unroll
    for (int kt = 0; kt < 4; ++kt)
      #pragma unroll
      for (int j = 0; j < 8; ++j)
        bf[nt][kt][j] =
            (_Float16)W2[(kt * 32 + lq * 8 + j) * 512 + w * 64 + nt * 16 + l15];

  float b2r[8];
  #pragma unroll
  for (int c = 0; c < 8; ++c) b2r[c] = b2[hx * 8 + c];   // hx<=63 safe for all lanes

  // ---- z0 (owners only)
  float z = 0.0f;
  if (owner) {
    const float* cb = coeffs + (size_t)(row0 + r) * (LM1 * 32);
    float x0[8];
    #pragma unroll
    for (int c = 0; c < 8; ++c) x0[c] = cb[c];
    float acc = bi2[hx];
    for (int j = 0; j < 20; ++j) {
      float u = bi1[j];
      #pragma unroll
      for (int c = 0; c < 8; ++c) u += x0[c] * Wi1[c * 20 + j];
      acc += fmaxf(u, 0.0f) * Wi2[j * 64 + hx];
    }
    z = fast_tanh(acc);
    out[(size_t)(row0 + r) * 8192 + hx] = z;
  }

  // ---- coeff prefetch registers (threads 0..31: rg=t>>3, cg=t&7)
  const int rg = (t >> 3) & 3, cg = t & 7;
  const float* cbp = coeffs + (size_t)(row0 + rg) * (LM1 * 32);
  float pb = 0.f, pc = 0.f, pd = 0.f, pbn = 0.f;
  if (t < 32) { pb = cbp[8 + cg]; pc = cbp[16 + cg]; pd = cbp[24 + cg]; pbn = cbp[40 + cg]; }

  for (int i = 0; i < LM1; ++i) {
    if (t < 32) {
      gds[i & 1][0][rg][cg] = pb;
      gds[i & 1][1][rg][cg] = pb + pc + 0.75f * pd;
      gds[i & 1][2][rg][cg] = (i < LM1 - 1) ? pbn : fmaf(3.0f, pd, fmaf(2.0f, pc, pb));
      if (i + 1 < LM1) {           // prefetch next stage (latency spans whole stage)
        const float* nb = cbp + (size_t)(i + 1) * 32;
        pb = nb[8 + cg]; pc = nb[16 + cg]; pd = nb[24 + cg];
        pbn = (i + 2 < LM1) ? nb[40 + cg] : 0.0f;
      }
    }

    float ksum = 0.0f, kprev = 0.0f;
    #pragma unroll
    for (int s = 0; s < 4; ++s) {
      const float coef = (s == 0) ? 0.0f : (s == 3) ? 1.0f : 0.5f;
      const float ts   = (float)i + ((s == 0) ? 0.0f : (s == 3) ? 1.0f : 0.5f);
      const int   gi   = (s == 0) ? 0 : (s == 3) ? 2 : 1;

      // Phase A: owners stage zs into A-layout LDS
      if (owner) zsb[r * 72 + hx] = (_Float16)(z + coef * kprev);
      __syncthreads();

      // Phase B: h-tile via MFMA (wave w -> cols 16w..16w+15)
      {
        half8_t a0 = *(const half8_t*)(zsb + l15 * 72 + lq * 8);
        half8_t a1 = *(const half8_t*)(zsb + l15 * 72 + 32 + lq * 8);
        f32x4 hd = {0.f, 0.f, 0.f, 0.f};
        hd = __builtin_amdgcn_mfma_f32_16x16x32_f16(a0, bB[0], hd, 0, 0, 0);
        hd = __builtin_amdgcn_mfma_f32_16x16x32_f16(a1, bB[1], hd, 0, 0, 0);
        if (lane < 16) {           // rows 0..3 live in regs .x...w of lanes 0..15
          const float hb = fmaf(ts, w1t_c, b1_c);
          const int col = w * 16 + lane;
          hA[0 * 136 + col] = (_Float16)fmaxf(hd.x + hb, 0.0f);
          hA[1 * 136 + col] = (_Float16)fmaxf(hd.y + hb, 0.0f);
          hA[2 * 136 + col] = (_Float16)fmaxf(hd.z + hb, 0.0f);
          hA[3 * 136 + col] = (_Float16)fmaxf(hd.w + hb, 0.0f);
        }
      }
      __syncthreads();

      // Phase C: D = h @ W2 (wave w -> cols 64w..64w+63), 4 acc chains
      {
        half8_t ha[4];
        #pragma unroll
        for (int kt = 0; kt < 4; ++kt)
          ha[kt] = *(const half8_t*)(hA + l15 * 136 + kt * 32 + lq * 8);
        f32x4 d0 = {0.f,0.f,0.f,0.f}, d1 = d0, d2 = d0, d3 = d0;
        #pragma unroll
        for (int kt = 0; kt < 4; ++kt) {
          d0 = __builtin_amdgcn_mfma_f32_16x16x32_f16(ha[kt], bf[0][kt], d0, 0, 0, 0);
          d1 = __builtin_amdgcn_mfma_f32_16x16x32_f16(ha[kt], bf[1][kt], d1, 0, 0, 0);
          d2 = __builtin_amdgcn_mfma_f32_16x16x32_f16(ha[kt], bf[2][kt], d2, 0, 0, 0);
          d3 = __builtin_amdgcn_mfma_f32_16x16x32_f16(ha[kt], bf[3][kt], d3, 0, 0, 0);
        }
        if (lane < 16) {
          f32x4 dd[4] = {d0, d1, d2, d3};
          #pragma unroll
          for (int nt = 0; nt < 4; ++nt) {
            const int cl = nt * 16 + lane;         // local col 0..63
            *(f32x4*)(&fwb[w][36 * (cl >> 3) + 4 * (cl & 7)]) = dd[nt];
          }
        }
      }
      asm volatile("s_waitcnt lgkmcnt(0)" ::: "memory");  // within-wave handoff

      // kc (owners): 8 channels, conflict-free reads (bank = 4(hxl+c)+r)
      if (owner) {
        const f32x4 g0 = *(const f32x4*)&gds[i & 1][gi][r][0];
        const f32x4 g1 = *(const f32x4*)&gds[i & 1][gi][r][4];
        const float gg[8] = {g0.x, g0.y, g0.z, g0.w, g1.x, g1.y, g1.z, g1.w};
        const float* fp = &fwb[w][36 * hxl + r];
        float kcv = 0.0f;
        #pragma unroll
        for (int c = 0; c < 8; ++c)
          kcv += fast_tanh(fp[4 * c] + b2r[c]) * gg[c];
        kprev = kcv;
        ksum += ((s == 1 || s == 2) ? 2.0f : 1.0f) * kcv;
      }
    }
    if (owner) {
      z += ksum * (1.0f / 6.0f);
      out[(size_t)(row0 + r) * 8192 + (size_t)(i + 1) * 64 + hx] = z;
    }
  }
}

extern "C" void kernel_launch(void* const* d_in, const int* in_sizes, int n_in,
                              void* d_out, int out_size, void* d_ws, size_t ws_size,
                              hipStream_t stream) {
  const float* coeffs = (const float*)d_in[0];
  const float* Wi1    = (const float*)d_in[1];
  const float* bi1    = (const float*)d_in[2];
  const float* Wi2    = (const float*)d_in[3];
  const float* bi2    = (const float*)d_in[4];
  const float* W1     = (const float*)d_in[5];
  const float* b1     = (const float*)d_in[6];
  const float* W2     = (const float*)d_in[7];
  const float* b2     = (const float*)d_in[8];
  float* out          = (float*)d_out;
  (void)in_sizes; (void)n_in; (void)out_size; (void)d_ws; (void)ws_size;
  cde_kernel<<<256, NTHR, 0, stream>>>(coeffs, Wi1, bi1, Wi2, bi2,
                                       W1, b1, W2, b2, out);
}

// Round 4
// 537.633 us; speedup vs baseline: 2.7861x; 1.1067x over previous
//
#include <hip/hip_runtime.h>
#include <stdint.h>

#define LM1  127
#define NTHR 1024

typedef _Float16 half8_t __attribute__((ext_vector_type(8)));
typedef float    f32x4   __attribute__((ext_vector_type(4)));
typedef float    f32x2   __attribute__((ext_vector_type(2)));

__device__ __forceinline__ float fast_tanh(float x) {
  float e = __expf(2.0f * x);
  return 1.0f - 2.0f * __builtin_amdgcn_rcpf(e + 1.0f);
}

// 256 blocks x 4 rows x 16 waves (4 waves/SIMD). MFMA 16x16x32 f16, weights
// in registers as B-fragments. LDS fragment buffers use 16B-chunk layout so
// A-frag reads are base+16*lane (conflict-free, m97 pattern):
//   zsb chunk(kh,lq,m), hA chunk(kt,lq,m) -> read addr = 16*lane (+512*kh/kt*2)
// Phase B: waves 0..7 own h-cols [16w,16w+16) (2 MFMA).
// Phase C: wave w owns f-cols [32w,32w+32) (8 MFMA, 2 chains).
// kc: all 64 lanes, 2 channels each (lane = q*16 + hxl*4 + r, c = 2q+j),
// combined via shfl_xor(16) + shfl_xor(32); finalists = lanes 0..15.
__global__ void __launch_bounds__(NTHR, 4) cde_kernel(
    const float* __restrict__ coeffs,
    const float* __restrict__ Wi1, const float* __restrict__ bi1,
    const float* __restrict__ Wi2, const float* __restrict__ bi2,
    const float* __restrict__ W1,  const float* __restrict__ b1,
    const float* __restrict__ W2,  const float* __restrict__ b2,
    float* __restrict__ out)
{
  __shared__ _Float16 zsb[1024];       // 2 KB: chunk = kh*64 + lq*16 + m
  __shared__ _Float16 hA [2048];       // 4 KB: chunk = kt*64 + lq*16 + m
  __shared__ float    fwb[16][144];    // 9 KB: per-wave D: word = 36*(cl>>3)+4*(cl&7)+r
  __shared__ float    gds[2][3][4][8]; // double-buffered dXdt at fr=0,0.5,1

  const int t    = threadIdx.x;
  const int lane = t & 63;
  const int w    = t >> 6;            // wave 0..15
  const int l15  = lane & 15;
  const int lq   = lane >> 4;         // quad 0..3
  const int r    = lane & 3;
  const int row0 = blockIdx.x * 4;

  // zero chunk buffers once (rows m>=4 stay zero; safety for garbage)
  for (int u = t; u < 512;  u += NTHR) ((uint32_t*)zsb)[u] = 0u;
  for (int u = t; u < 1024; u += NTHR) ((uint32_t*)hA)[u]  = 0u;

  // ---- W1 -> B-fragments (waves 0..7 only) + epilogue constants
  half8_t bB[2] = {};
  float w1t_c = 0.f, b1_c = 0.f;
  if (w < 8) {
    #pragma unroll
    for (int kt = 0; kt < 2; ++kt)
      #pragma unroll
      for (int j = 0; j < 8; ++j)
        bB[kt][j] = (_Float16)W1[(1 + kt * 32 + lq * 8 + j) * 128 + w * 16 + l15];
    w1t_c = W1[w * 16 + l15];
    b1_c  = b1[w * 16 + l15];
  }

  // ---- W2 -> B-fragments: 2 n-tiles x 4 k-tiles (cols 32w + nt*16 + l15)
  half8_t bf[2][4];
  #pragma unroll
  for (int nt = 0; nt < 2; ++nt)
    #pragma unroll
    for (int kt = 0; kt < 4; ++kt)
      #pragma unroll
      for (int j = 0; j < 8; ++j)
        bf[nt][kt][j] =
            (_Float16)W2[(kt * 32 + lq * 8 + j) * 512 + w * 32 + nt * 16 + l15];

  // ---- kc constants (all 64 lanes): lane = q*16 + hxl*4 + r, channels 2q, 2q+1
  const int q    = lane >> 4;
  const int hxlk = (lane >> 2) & 3;
  const int hxk  = w * 4 + hxlk;
  const float b2r0 = b2[hxk * 8 + 2 * q];
  const float b2r1 = b2[hxk * 8 + 2 * q + 1];

  // ---- owner constants (lanes 0..15): (r = lane&3, hx = w*4 + (lane>>2))
  const int hx = w * 4 + (lane >> 2);
  _Float16* zwp;                        // zsb write slot for this owner
  {
    const int kh = hx >> 5, lqw = (hx >> 3) & 3, j = hx & 7;
    zwp = &zsb[8 * (kh * 64 + lqw * 16 + r) + j];
  }
  _Float16* hwp;                        // hA write base (phase-B epilogue, waves<8)
  {
    const int col = 16 * w + l15;       // valid for w<8, lane<16
    const int ktw = (col >> 5) & 3, lqw2 = (col >> 3) & 3, j2 = col & 7;
    hwp = &hA[8 * (ktw * 64 + lqw2 * 16) + j2];
  }
  float* const fsp = &fwb[w][36 * (l15 >> 3) + 4 * (l15 & 7)];  // D store base
  const float* const frp = &fwb[w][36 * hxlk + 8 * q + r];      // kc read base

  // ---- z0 (lanes 0..15 of each wave)
  float z = 0.0f;
  if (lane < 16) {
    const float* cb = coeffs + (size_t)(row0 + r) * (LM1 * 32);
    float x0[8];
    #pragma unroll
    for (int c = 0; c < 8; ++c) x0[c] = cb[c];
    float acc = bi2[hx];
    for (int j = 0; j < 20; ++j) {
      float u = bi1[j];
      #pragma unroll
      for (int c = 0; c < 8; ++c) u += x0[c] * Wi1[c * 20 + j];
      acc += fmaxf(u, 0.0f) * Wi2[j * 64 + hx];
    }
    z = fast_tanh(acc);
    out[(size_t)(row0 + r) * 8192 + hx] = z;
  }

  // ---- coeff prefetch (threads 0..31: rg = t>>3, cg = t&7)
  const int rg = (t >> 3) & 3, cg = t & 7;
  const float* cbp = coeffs + (size_t)(row0 + rg) * (LM1 * 32);
  float pb = 0.f, pc = 0.f, pd = 0.f, pbn = 0.f;
  if (t < 32) { pb = cbp[8 + cg]; pc = cbp[16 + cg]; pd = cbp[24 + cg]; pbn = cbp[40 + cg]; }

  __syncthreads();   // init-zero + weight staging complete

  for (int i = 0; i < LM1; ++i) {
    if (t < 32) {
      gds[i & 1][0][rg][cg] = pb;
      gds[i & 1][1][rg][cg] = pb + pc + 0.75f * pd;
      gds[i & 1][2][rg][cg] = (i < LM1 - 1) ? pbn : fmaf(3.0f, pd, fmaf(2.0f, pc, pb));
      if (i + 1 < LM1) {
        const float* nb = cbp + (size_t)(i + 1) * 32;
        pb = nb[8 + cg]; pc = nb[16 + cg]; pd = nb[24 + cg];
        pbn = (i + 2 < LM1) ? nb[40 + cg] : 0.0f;
      }
    }

    float ksum = 0.0f, kprev = 0.0f;
    #pragma unroll
    for (int s = 0; s < 4; ++s) {
      const float coef = (s == 0) ? 0.0f : (s == 3) ? 1.0f : 0.5f;
      const float ts   = (float)i + ((s == 0) ? 0.0f : (s == 3) ? 1.0f : 0.5f);
      const int   gi   = (s == 0) ? 0 : (s == 3) ? 2 : 1;

      // Phase A: owners stage zs (single b16, conflict-light)
      if (lane < 16) *zwp = (_Float16)(z + coef * kprev);
      __syncthreads();

      // Phase B: waves 0..7 compute h-tile w (reads at 16*lane: conflict-free)
      if (w < 8) {
        const half8_t a0 = *(const half8_t*)(zsb + 8 * lane);
        const half8_t a1 = *(const half8_t*)(zsb + 512 + 8 * lane);
        f32x4 hd = {0.f, 0.f, 0.f, 0.f};
        hd = __builtin_amdgcn_mfma_f32_16x16x32_f16(a0, bB[0], hd, 0, 0, 0);
        hd = __builtin_amdgcn_mfma_f32_16x16x32_f16(a1, bB[1], hd, 0, 0, 0);
        if (lane < 16) {
          const float hb = fmaf(ts, w1t_c, b1_c);
          hwp[0]  = (_Float16)fmaxf(hd.x + hb, 0.0f);
          hwp[8]  = (_Float16)fmaxf(hd.y + hb, 0.0f);
          hwp[16] = (_Float16)fmaxf(hd.z + hb, 0.0f);
          hwp[24] = (_Float16)fmaxf(hd.w + hb, 0.0f);
        }
      }
      __syncthreads();

      // Phase C: wave w -> f-cols [32w,32w+32) (reads at 16*lane + 1024*kt)
      {
        half8_t ha[4];
        #pragma unroll
        for (int kt = 0; kt < 4; ++kt)
          ha[kt] = *(const half8_t*)(hA + 512 * kt + 8 * lane);
        f32x4 d0 = {0.f, 0.f, 0.f, 0.f}, d1 = d0;
        #pragma unroll
        for (int kt = 0; kt < 4; ++kt) {
          d0 = __builtin_amdgcn_mfma_f32_16x16x32_f16(ha[kt], bf[0][kt], d0, 0, 0, 0);
          d1 = __builtin_amdgcn_mfma_f32_16x16x32_f16(ha[kt], bf[1][kt], d1, 0, 0, 0);
        }
        if (lane < 16) {
          *(f32x4*)(fsp)      = d0;    // cols lane,     rows 0..3 (2-way free)
          *(f32x4*)(fsp + 72) = d1;    // cols 16+lane
        }
      }
      asm volatile("s_waitcnt lgkmcnt(0)" ::: "memory");  // within-wave handoff

      // kc: 2 channels/lane, butterfly combine; finalists lanes 0..15
      {
        const float v0 = frp[0], v1 = frp[4];
        const f32x2 gv = *(const f32x2*)&gds[i & 1][gi][r][2 * q];
        float kcv = fast_tanh(v0 + b2r0) * gv.x + fast_tanh(v1 + b2r1) * gv.y;
        kcv += __shfl_xor(kcv, 16, 64);
        kcv += __shfl_xor(kcv, 32, 64);
        kprev = kcv;
        ksum += ((s == 1 || s == 2) ? 2.0f : 1.0f) * kcv;
      }
    }
    if (lane < 16) {
      z += ksum * (1.0f / 6.0f);
      out[(size_t)(row0 + r) * 8192 + (size_t)(i + 1) * 64 + hx] = z;
    }
  }
}

extern "C" void kernel_launch(void* const* d_in, const int* in_sizes, int n_in,
                              void* d_out, int out_size, void* d_ws, size_t ws_size,
                              hipStream_t stream) {
  const float* coeffs = (const float*)d_in[0];
  const float* Wi1    = (const float*)d_in[1];
  const float* bi1    = (const float*)d_in[2];
  const float* Wi2    = (const float*)d_in[3];
  const float* bi2    = (const float*)d_in[4];
  const float* W1     = (const float*)d_in[5];
  const float* b1     = (const float*)d_in[6];
  const float* W2     = (const float*)d_in[7];
  const float* b2     = (const float*)d_in[8];
  float* out          = (float*)d_out;
  (void)in_sizes; (void)n_in; (void)out_size; (void)d_ws; (void)ws_size;
  cde_kernel<<<256, NTHR, 0, stream>>>(coeffs, Wi1, bi1, Wi2, bi2,
                                       W1, b1, W2, b2, out);
}